// Round 1
// baseline (412.613 us; speedup 1.0000x reference)
//
#include <hip/hip_runtime.h>
#include <hip/hip_bf16.h>
#include <stdint.h>

// Problem constants: B=4, T=256, U=64, D=512, H=512, V=1024
//   enc: (4,256,512)=524288 f32   dec: (4,64,512)=131072 f32
//   w1: (512,1024)=524288 f32     b1: 512 f32    w2: (1024,512)=524288 f32
//   out: (4,256,64,1024)=67108864 f32
// GEMM2: M=65536 (b*t*u), K=512 (h... wait K=H=512), N=1024 (v)

typedef __bf16 bf16_t;
typedef bf16_t bf16x8 __attribute__((ext_vector_type(8)));
typedef float f32x4 __attribute__((ext_vector_type(4)));

#define GLD16(gp, lp)                                                          \
  __builtin_amdgcn_global_load_lds(                                            \
      (const __attribute__((address_space(1))) void*)(gp),                     \
      (__attribute__((address_space(3))) void*)(lp), 16, 0, 0)

__device__ __forceinline__ unsigned short f2bf(float f) {
  unsigned int u = __float_as_uint(f);
  unsigned int r = (u + 0x7FFFu + ((u >> 16) & 1u)) >> 16;
  return (unsigned short)r;
}

__device__ __forceinline__ float gelu_f(float x) {
  // jax.nn.gelu approximate=True: 0.5x(1+tanh(sqrt(2/pi)(x+0.044715 x^3)))
  float t = tanhf(0.7978845608028654f * x + 0.035677408136300125f * (x * x * x));
  return 0.5f * x * (1.0f + t);
}

// ---------------------------------------------------------------------------
// prep: fp32 -> bf16 conversions. Output element regions (ushort units):
//   [0,524288)        enc
//   [524288,655360)   dec
//   [655360,917504)   w_enc = w1[:, :512]   (512x512, K-contig)
//   [917504,1179648)  w_dec = w1[:, 512:]
//   [1179648,1703936) w2 (1024x512, K-contig)
// 1703936/4 elems per thread = 425984 threads = 1664 blocks x 256
// ---------------------------------------------------------------------------
__global__ __launch_bounds__(256) void prep_kernel(
    const float* __restrict__ enc, const float* __restrict__ dec,
    const float* __restrict__ w1, const float* __restrict__ w2,
    unsigned short* __restrict__ o) {
  int i = (blockIdx.x * 256 + threadIdx.x) * 4;
  float4 v;
  if (i < 524288) {
    v = *(const float4*)(enc + i);
  } else if (i < 655360) {
    v = *(const float4*)(dec + (i - 524288));
  } else if (i < 917504) {
    int j = i - 655360;
    v = *(const float4*)(w1 + (j >> 9) * 1024 + (j & 511));
  } else if (i < 1179648) {
    int j = i - 917504;
    v = *(const float4*)(w1 + (j >> 9) * 1024 + 512 + (j & 511));
  } else {
    v = *(const float4*)(w2 + (i - 1179648));
  }
  ushort4 r;
  r.x = f2bf(v.x); r.y = f2bf(v.y); r.z = f2bf(v.z); r.w = f2bf(v.w);
  *(ushort4*)(o + i) = r;
}

// ---------------------------------------------------------------------------
// hidden: bf16 hidden[m][h] = gelu(enc_proj[m>>6][h] + dec_proj[dr(m)][h] + b1[h])
//   m in [0,65536), h in [0,512). dr(m) = (m>>14)*64 + (m&63).
// One thread per 4 h. 8388608 threads = 32768 blocks x 256.
// ---------------------------------------------------------------------------
__global__ __launch_bounds__(256) void hidden_kernel(
    const float* __restrict__ ep, const float* __restrict__ dp,
    const float* __restrict__ b1, unsigned short* __restrict__ o) {
  int g = blockIdx.x * 256 + threadIdx.x;
  int m = g >> 7;
  int h = (g & 127) << 2;
  int er = m >> 6;
  int dr = ((m >> 14) << 6) | (m & 63);
  float4 e = *(const float4*)(ep + er * 512 + h);
  float4 d = *(const float4*)(dp + dr * 512 + h);
  float4 b = *(const float4*)(b1 + h);
  ushort4 r;
  r.x = f2bf(gelu_f(e.x + d.x + b.x));
  r.y = f2bf(gelu_f(e.y + d.y + b.y));
  r.z = f2bf(gelu_f(e.z + d.z + b.z));
  r.w = f2bf(gelu_f(e.w + d.w + b.w));
  *(ushort4*)(o + (size_t)g * 4) = r;
}

// ---------------------------------------------------------------------------
// gemm_bt: C[M][N] f32 = A[M][K] bf16 * B[N][K]^T bf16   (both K-contiguous)
// 128x128 tile / block, 256 threads = 4 waves (2x2 of 64x64), BK=32,
// 16x16x32 bf16 MFMA, 4x4 frags/wave, global_load_lds width 16. (m97 shape)
// Requires M%128==0, N%128==0, K%32==0.
// ---------------------------------------------------------------------------
__global__ __launch_bounds__(256) void gemm_bt(
    const bf16_t* __restrict__ A, const bf16_t* __restrict__ B,
    float* __restrict__ C, int M, int N, int K) {
  __shared__ bf16_t sA[128 * 32];
  __shared__ bf16_t sB[128 * 32];

  const int tid = threadIdx.x;
  const int lane = tid & 63;
  const int w = tid >> 6;
  const int m0 = blockIdx.y * 128;
  const int n0 = blockIdx.x * 128;
  const int wm = (w >> 1) * 64;  // wave sub-tile origin in tile
  const int wn = (w & 1) * 64;

  // staging geometry: chunk q = w*2+c covers LDS elems [q*512, q*512+512)
  //   = tile rows [q*16, q*16+16); lane covers row q*16 + lane/4,
  //   cols [(lane&3)*8, +8)  -> 16 bytes
  const int colS = (lane & 3) * 8;
  const int rA0 = (w * 2 + 0) * 16 + (lane >> 2);
  const int rA1 = (w * 2 + 1) * 16 + (lane >> 2);
  const bf16_t* gA0 = A + (size_t)(m0 + rA0) * K + colS;
  const bf16_t* gA1 = A + (size_t)(m0 + rA1) * K + colS;
  const bf16_t* gB0 = B + (size_t)(n0 + rA0) * K + colS;
  const bf16_t* gB1 = B + (size_t)(n0 + rA1) * K + colS;
  bf16_t* lA0 = sA + (w * 2 + 0) * 512;
  bf16_t* lA1 = sA + (w * 2 + 1) * 512;
  bf16_t* lB0 = sB + (w * 2 + 0) * 512;
  bf16_t* lB1 = sB + (w * 2 + 1) * 512;

  // fragment read offsets (units of bf16x8): A[m=lane&15][k=(lane>>4)*8 + j]
  const int offA = ((wm + (lane & 15)) * 32 + (lane >> 4) * 8) >> 3;
  const int offB = ((wn + (lane & 15)) * 32 + (lane >> 4) * 8) >> 3;
  const bf16x8* pA = (const bf16x8*)sA;
  const bf16x8* pB = (const bf16x8*)sB;

  f32x4 acc[4][4] = {};

  for (int kt = 0; kt < K; kt += 32) {
    GLD16(gA0 + kt, lA0);
    GLD16(gA1 + kt, lA1);
    GLD16(gB0 + kt, lB0);
    GLD16(gB1 + kt, lB1);
    __syncthreads();

    bf16x8 af[4], bb[4];
#pragma unroll
    for (int i = 0; i < 4; i++) af[i] = pA[offA + i * 64];
#pragma unroll
    for (int j = 0; j < 4; j++) bb[j] = pB[offB + j * 64];
#pragma unroll
    for (int i = 0; i < 4; i++)
#pragma unroll
      for (int j = 0; j < 4; j++)
        acc[i][j] = __builtin_amdgcn_mfma_f32_16x16x32_bf16(af[i], bb[j],
                                                            acc[i][j], 0, 0, 0);
    __syncthreads();
  }

  // epilogue: C/D layout col=lane&15, row=(lane>>4)*4+r
  const int crow = m0 + wm + (lane >> 4) * 4;
  const int ccol = n0 + wn + (lane & 15);
  float* Cp = C + (size_t)crow * N + ccol;
#pragma unroll
  for (int i = 0; i < 4; i++)
#pragma unroll
    for (int r = 0; r < 4; r++)
#pragma unroll
      for (int j = 0; j < 4; j++)
        Cp[(size_t)(i * 16 + r) * N + j * 16] = acc[i][j][r];
}

// ---------------------------------------------------------------------------
extern "C" void kernel_launch(void* const* d_in, const int* in_sizes, int n_in,
                              void* d_out, int out_size, void* d_ws,
                              size_t ws_size, hipStream_t stream) {
  const float* enc = (const float*)d_in[0];
  const float* dec = (const float*)d_in[1];
  const float* w1  = (const float*)d_in[2];
  const float* b1  = (const float*)d_in[3];
  const float* w2  = (const float*)d_in[4];
  float* out = (float*)d_out;

  // workspace layout
  unsigned short* bf      = (unsigned short*)d_ws;
  unsigned short* ws_enc  = bf;             // 524288
  unsigned short* ws_dec  = bf + 524288;    // 131072
  unsigned short* ws_wenc = bf + 655360;    // 262144
  unsigned short* ws_wdec = bf + 917504;    // 262144
  unsigned short* ws_w2   = bf + 1179648;   // 524288; bf16 end @ 3407872 B
  float* encp = (float*)((char*)d_ws + 3407872);   // 1024x512 f32 (2 MB)
  float* decp = encp + 524288;                     // 256x512 f32 (0.5 MB)
  unsigned short* hid = (unsigned short*)(decp + 131072);  // 65536x512 bf16 (64 MB)

  prep_kernel<<<1664, 256, 0, stream>>>(enc, dec, w1, w2, bf);

  // enc_proj = enc(1024x512) x w_enc(512x512)^T
  gemm_bt<<<dim3(4, 8), 256, 0, stream>>>((const bf16_t*)ws_enc,
                                          (const bf16_t*)ws_wenc, encp,
                                          1024, 512, 512);
  // dec_proj = dec(256x512) x w_dec(512x512)^T
  gemm_bt<<<dim3(4, 2), 256, 0, stream>>>((const bf16_t*)ws_dec,
                                          (const bf16_t*)ws_wdec, decp,
                                          256, 512, 512);

  hidden_kernel<<<32768, 256, 0, stream>>>(encp, decp, b1, hid);

  // logits = hidden(65536x512) x w2(1024x512)^T
  gemm_bt<<<dim3(8, 512), 256, 0, stream>>>((const bf16_t*)hid,
                                            (const bf16_t*)ws_w2, out,
                                            65536, 1024, 512);
}

// Round 2
// 384.013 us; speedup vs baseline: 1.0745x; 1.0745x over previous
//
#include <hip/hip_runtime.h>
#include <hip/hip_bf16.h>
#include <stdint.h>

// B=4, T=256, U=64, D=512, H=512, V=1024
// gemm2: M=65536, K=512, N=1024 -> 68.7 GFLOP, out 268 MB fp32

typedef __bf16 bf16_t;
typedef bf16_t bf16x8 __attribute__((ext_vector_type(8)));
typedef float f32x4 __attribute__((ext_vector_type(4)));
typedef unsigned short u16x8 __attribute__((ext_vector_type(8)));

#define GLD16(gp, lp)                                                          \
  __builtin_amdgcn_global_load_lds(                                            \
      (const __attribute__((address_space(1))) void*)(gp),                     \
      (__attribute__((address_space(3))) void*)(lp), 16, 0, 0)

__device__ __forceinline__ unsigned short f2bf(float f) {
  unsigned int u = __float_as_uint(f);
  return (unsigned short)((u + 0x7FFFu + ((u >> 16) & 1u)) >> 16);
}

// gelu(x) = x * sigmoid(1.5957691216x + 0.0713548136x^3)  (tanh-approx form)
__device__ __forceinline__ float gelu_f(float x) {
  float t = 1.5957691216057308f * x + 0.07135481283867141f * (x * x * x);
  float e = __expf(-t);                       // v_exp_f32 path
  return x * __builtin_amdgcn_rcpf(1.0f + e); // v_rcp_f32
}

// ---------------------------------------------------------------------------
// prep: fp32 -> bf16. Regions (ushort units):
//   [0,524288) enc | [524288,655360) dec | [655360,917504) w_enc |
//   [917504,1179648) w_dec | [1179648,1703936) w2
// ---------------------------------------------------------------------------
__global__ __launch_bounds__(256) void prep_kernel(
    const float* __restrict__ enc, const float* __restrict__ dec,
    const float* __restrict__ w1, const float* __restrict__ w2,
    unsigned short* __restrict__ o) {
  int i = (blockIdx.x * 256 + threadIdx.x) * 4;
  float4 v;
  if (i < 524288) {
    v = *(const float4*)(enc + i);
  } else if (i < 655360) {
    v = *(const float4*)(dec + (i - 524288));
  } else if (i < 917504) {
    int j = i - 655360;
    v = *(const float4*)(w1 + (j >> 9) * 1024 + (j & 511));
  } else if (i < 1179648) {
    int j = i - 917504;
    v = *(const float4*)(w1 + (j >> 9) * 1024 + 512 + (j & 511));
  } else {
    v = *(const float4*)(w2 + (i - 1179648));
  }
  ushort4 r;
  r.x = f2bf(v.x); r.y = f2bf(v.y); r.z = f2bf(v.z); r.w = f2bf(v.w);
  *(ushort4*)(o + i) = r;
}

// ---------------------------------------------------------------------------
// hidden: bf16 hid[m][h] = gelu(ep[m>>6][h] + dp[dr(m)][h] + b1[h])
// 8 elems/thread. 16384 blocks x 256.
// ---------------------------------------------------------------------------
__global__ __launch_bounds__(256) void hidden_kernel(
    const float* __restrict__ ep, const float* __restrict__ dp,
    const float* __restrict__ b1, unsigned short* __restrict__ o) {
  int g = blockIdx.x * 256 + threadIdx.x;
  int m = g >> 6;
  int h = (g & 63) << 3;
  int er = m >> 6;
  int dr = ((m >> 14) << 6) | (m & 63);
  float4 e0 = *(const float4*)(ep + er * 512 + h);
  float4 e1 = *(const float4*)(ep + er * 512 + h + 4);
  float4 d0 = *(const float4*)(dp + dr * 512 + h);
  float4 d1 = *(const float4*)(dp + dr * 512 + h + 4);
  float4 b0 = *(const float4*)(b1 + h);
  float4 b1v = *(const float4*)(b1 + h + 4);
  u16x8 r;
  r[0] = f2bf(gelu_f(e0.x + d0.x + b0.x));
  r[1] = f2bf(gelu_f(e0.y + d0.y + b0.y));
  r[2] = f2bf(gelu_f(e0.z + d0.z + b0.z));
  r[3] = f2bf(gelu_f(e0.w + d0.w + b0.w));
  r[4] = f2bf(gelu_f(e1.x + d1.x + b1v.x));
  r[5] = f2bf(gelu_f(e1.y + d1.y + b1v.y));
  r[6] = f2bf(gelu_f(e1.z + d1.z + b1v.z));
  r[7] = f2bf(gelu_f(e1.w + d1.w + b1v.w));
  *(u16x8*)(o + (size_t)g * 8) = r;
}

// ---------------------------------------------------------------------------
// gemm_core: C[M][N] f32 = A[M][K] bf16 * B[N][K]^T bf16 (K-contig both).
// 128x128 tile, 256 thr (4 waves = 2x2 of 64x64), BK=64, XOR-swizzled LDS:
//   row r (128 B = 8 x 16B slots): matrix chunk c stored at slot c^(r&7).
//   GLD16 lane l of chunk q (rows q*8..+8): row q*8+(l>>3), fetches matrix
//   chunk (l&7)^(l>>3)  -> permutation within one 128 B segment (coalesced).
//   Frag read slot = (kk*4 + (lane>>4)) ^ (lane&7): 8 lanes/slot = uniform.
// ---------------------------------------------------------------------------
__device__ __forceinline__ void gemm_core(
    const bf16_t* __restrict__ A, const bf16_t* __restrict__ B,
    float* __restrict__ C, int m0, int n0, int N, int K) {
  __shared__ bf16_t sA[128 * 64];
  __shared__ bf16_t sB[128 * 64];

  const int tid = threadIdx.x;
  const int lane = tid & 63;
  const int w = tid >> 6;
  const int wm = (w >> 1) * 64;
  const int wn = (w & 1) * 64;

  // staging addresses
  const int srow = w * 32 + (lane >> 3);            // + j*8 per chunk j
  const int scol = (((lane & 7) ^ (lane >> 3)) << 3);
  const bf16_t* gA = A + (size_t)(m0 + srow) * K + scol;
  const bf16_t* gB = B + (size_t)(n0 + srow) * K + scol;

  // fragment read bases (bf16x8 units): (row)*8 + slot
  const int rowA = wm + (lane & 15);
  const int rowB = wn + (lane & 15);
  const int sw0 = (lane >> 4) ^ (lane & 7);
  const bf16x8* pA = (const bf16x8*)sA;
  const bf16x8* pB = (const bf16x8*)sB;

  f32x4 acc[4][4] = {};

  for (int kt = 0; kt < K; kt += 64) {
#pragma unroll
    for (int j = 0; j < 4; j++) {
      GLD16(gA + (size_t)(j * 8) * K + kt, sA + (w * 4 + j) * 512);
      GLD16(gB + (size_t)(j * 8) * K + kt, sB + (w * 4 + j) * 512);
    }
    __syncthreads();

#pragma unroll
    for (int kk = 0; kk < 2; kk++) {
      const int sw = sw0 ^ (kk << 2);
      bf16x8 af[4], bb[4];
#pragma unroll
      for (int i = 0; i < 4; i++) af[i] = pA[(rowA + i * 16) * 8 + sw];
#pragma unroll
      for (int j = 0; j < 4; j++) bb[j] = pB[(rowB + j * 16) * 8 + sw];
#pragma unroll
      for (int i = 0; i < 4; i++)
#pragma unroll
        for (int j = 0; j < 4; j++)
          acc[i][j] = __builtin_amdgcn_mfma_f32_16x16x32_bf16(
              af[i], bb[j], acc[i][j], 0, 0, 0);
    }
    __syncthreads();
  }

  // epilogue: C/D layout col=lane&15, row=(lane>>4)*4+r
  const int crow = m0 + wm + (lane >> 4) * 4;
  const int ccol = n0 + wn + (lane & 15);
  float* Cp = C + (size_t)crow * N + ccol;
#pragma unroll
  for (int i = 0; i < 4; i++)
#pragma unroll
    for (int r = 0; r < 4; r++)
#pragma unroll
      for (int j = 0; j < 4; j++)
        Cp[(size_t)(i * 16 + r) * N + j * 16] = acc[i][j][r];
}

__global__ __launch_bounds__(256) void gemm_big(
    const bf16_t* __restrict__ A, const bf16_t* __restrict__ B,
    float* __restrict__ C, int M, int N, int K) {
  gemm_core(A, B, C, blockIdx.y * 128, blockIdx.x * 128, N, K);
}

// fused projections: y<8 -> enc proj (1024x512), y>=8 -> dec proj (256x512)
__global__ __launch_bounds__(256) void proj_kernel(
    const bf16_t* __restrict__ encA, const bf16_t* __restrict__ wenc,
    float* __restrict__ encC, const bf16_t* __restrict__ decA,
    const bf16_t* __restrict__ wdec, float* __restrict__ decC) {
  int by = blockIdx.y;
  if (by < 8) {
    gemm_core(encA, wenc, encC, by * 128, blockIdx.x * 128, 512, 512);
  } else {
    gemm_core(decA, wdec, decC, (by - 8) * 128, blockIdx.x * 128, 512, 512);
  }
}

// ---------------------------------------------------------------------------
extern "C" void kernel_launch(void* const* d_in, const int* in_sizes, int n_in,
                              void* d_out, int out_size, void* d_ws,
                              size_t ws_size, hipStream_t stream) {
  const float* enc = (const float*)d_in[0];
  const float* dec = (const float*)d_in[1];
  const float* w1  = (const float*)d_in[2];
  const float* b1  = (const float*)d_in[3];
  const float* w2  = (const float*)d_in[4];
  float* out = (float*)d_out;

  unsigned short* bf      = (unsigned short*)d_ws;
  unsigned short* ws_enc  = bf;             // 524288
  unsigned short* ws_dec  = bf + 524288;    // 131072
  unsigned short* ws_wenc = bf + 655360;    // 262144
  unsigned short* ws_wdec = bf + 917504;    // 262144
  unsigned short* ws_w2   = bf + 1179648;   // 524288; end @ 3407872 B
  float* encp = (float*)((char*)d_ws + 3407872);          // 1024x512 f32
  float* decp = encp + 524288;                            // 256x512 f32
  unsigned short* hid = (unsigned short*)(decp + 131072); // 65536x512 bf16

  prep_kernel<<<1664, 256, 0, stream>>>(enc, dec, w1, w2, bf);

  proj_kernel<<<dim3(4, 10), 256, 0, stream>>>(
      (const bf16_t*)ws_enc, (const bf16_t*)ws_wenc, encp,
      (const bf16_t*)ws_dec, (const bf16_t*)ws_wdec, decp);

  hidden_kernel<<<16384, 256, 0, stream>>>(encp, decp, b1, hid);

  gemm_big<<<dim3(8, 512), 256, 0, stream>>>(
      (const bf16_t*)hid, (const bf16_t*)ws_w2, out, 65536, 1024, 512);
}